// Round 1
// baseline (189.050 us; speedup 1.0000x reference)
//
#include <hip/hip_runtime.h>
#include <math.h>

// Problem constants (reference: B=4, N=2048, TIMESTEPS=1000, speed=0.01)
#define TIMESTEPS 1000
constexpr int Bc = 4;
constexpr int Nc = 2048;
constexpr long long Ec = (long long)Nc * (Nc - 1) / 2;  // 2,096,128

// Kernel 1: stream the lower triangle, accumulate loss, one double partial per block.
// Lower-tri only facts:
//   adj0[i][j] (i>j) == adj_start[i][j];  x_t uses u[i][j];  q_target has only
//   4 distinct values per batch, indexed by (a0, x). Precompute into LDS.
__global__ __launch_bounds__(256) void diff_loss_kernel(
    const int* __restrict__ adj, const int* __restrict__ t,
    const float* __restrict__ u, const float* __restrict__ q,
    double* __restrict__ partials)
{
    __shared__ float tab[Bc][8];
    if (threadIdx.x < Bc) {
        int b = threadIdx.x;
        int tb = t[b];
        // Qt[k] built with ts=k+1: flip = 0.5*(1 - 0.98^(k+1))
        float f_t = 0.5f * (1.0f - powf(0.98f, (float)(tb + 1)));
        int tpe = (tb == 0) ? TIMESTEPS : tb;        // Qt[t-1], wrap -1 -> 999 (ts=1000)
        float f_p = 0.5f * (1.0f - powf(0.98f, (float)tpe));
        float f0  = 0.5f * (1.0f - 0.98f);           // Qt[0] flip
        float omf_t = 1.0f - f_t;
        tab[b][0] = f_t;        // probs[...,1] when a0==0
        tab[b][1] = omf_t;      // probs[...,1] when a0==1
        // q_target(a0,x) = lik1(x) * pri1(a0) / evid(a0,x); evid = (x==a0)?1-f_t:f_t
        tab[b][2] = f0          * f_p          / omf_t;  // a0=0,x=0
        tab[b][3] = (1.0f - f0) * f_p          / f_t;    // a0=0,x=1
        tab[b][4] = f0          * (1.0f - f_p) / f_t;    // a0=1,x=0
        tab[b][5] = (1.0f - f0) * (1.0f - f_p) / omf_t;  // a0=1,x=1
    }
    __syncthreads();

    // Flat grid-stride over groups of 4 consecutive j. Layout: b (2) | i (11) | jg (9)
    const int totalGroups = Bc * Nc * (Nc / 4);      // 4,194,304
    const int stride = gridDim.x * blockDim.x;
    double acc = 0.0;
    for (int g = blockIdx.x * blockDim.x + threadIdx.x; g < totalGroups; g += stride) {
        int b   = g >> 20;              // / (2048*512)
        int rem = g & ((1 << 20) - 1);
        int i   = rem >> 9;
        int j0  = (rem & 511) << 2;
        if (j0 >= i) continue;          // whole group on/above diagonal

        long long base = ((long long)b << 22) + (i << 11) + j0;
        const int4   a4 = *(const int4*)(adj + base);   // 16B aligned (j0 % 4 == 0)
        const float4 u4 = *(const float4*)(u + base);

        float p0   = tab[b][0], p1   = tab[b][1];
        float qt00 = tab[b][2], qt01 = tab[b][3];
        float qt10 = tab[b][4], qt11 = tab[b][5];

        long long e0 = (long long)b * Ec + (((long long)i * (i - 1)) >> 1) + j0;

        int   aa[4] = {a4.x, a4.y, a4.z, a4.w};
        float uu[4] = {u4.x, u4.y, u4.z, u4.w};
        float s = 0.0f;
        #pragma unroll
        for (int k = 0; k < 4; ++k) {
            if (j0 + k < i) {           // predicate: strict lower triangle only
                int   a0  = aa[k];
                float ps  = a0 ? p1 : p0;
                int   x   = (uu[k] < ps) ? 1 : 0;
                float qtv = a0 ? (x ? qt11 : qt10) : (x ? qt01 : qt00);
                float qv  = q[e0 + k];
                float l = fmaxf(qv, 0.0f) - qv * qtv + log1pf(expf(-fabsf(qv)));
                s += l;
            }
        }
        acc += (double)s;
    }

    // wave (64) shuffle reduce, then cross-wave via LDS
    for (int off = 32; off > 0; off >>= 1)
        acc += __shfl_down(acc, off, 64);
    __shared__ double wsum[4];
    int lane = threadIdx.x & 63, wid = threadIdx.x >> 6;
    if (lane == 0) wsum[wid] = acc;
    __syncthreads();
    if (threadIdx.x == 0)
        partials[blockIdx.x] = wsum[0] + wsum[1] + wsum[2] + wsum[3];
}

// Kernel 2: reduce per-block partials, write mean as f32.
__global__ __launch_bounds__(256) void final_reduce_kernel(
    const double* __restrict__ partials, int nb, float* __restrict__ out)
{
    double acc = 0.0;
    for (int idx = threadIdx.x; idx < nb; idx += blockDim.x)
        acc += partials[idx];
    for (int off = 32; off > 0; off >>= 1)
        acc += __shfl_down(acc, off, 64);
    __shared__ double wsum[4];
    int lane = threadIdx.x & 63, wid = threadIdx.x >> 6;
    if (lane == 0) wsum[wid] = acc;
    __syncthreads();
    if (threadIdx.x == 0)
        out[0] = (float)((wsum[0] + wsum[1] + wsum[2] + wsum[3]) /
                         (double)(Bc * Ec));
}

extern "C" void kernel_launch(void* const* d_in, const int* in_sizes, int n_in,
                              void* d_out, int out_size, void* d_ws, size_t ws_size,
                              hipStream_t stream) {
    const int*   adj = (const int*)d_in[0];   // adj_start (B,N,N) int32
    const int*   t   = (const int*)d_in[1];   // t (B,) int32
    const float* u   = (const float*)d_in[2]; // u (B,N,N) f32
    const float* q   = (const float*)d_in[3]; // q_approx (B,E) f32
    float*  out      = (float*)d_out;
    double* partials = (double*)d_ws;         // NB doubles (16 KB)

    const int NB = 2048;
    diff_loss_kernel<<<NB, 256, 0, stream>>>(adj, t, u, q, partials);
    final_reduce_kernel<<<1, 256, 0, stream>>>(partials, NB, out);
}

// Round 2
// 164.720 us; speedup vs baseline: 1.1477x; 1.1477x over previous
//
#include <hip/hip_runtime.h>
#include <math.h>

// Problem constants (reference: B=4, N=2048, TIMESTEPS=1000, speed=0.01)
#define TIMESTEPS 1000
constexpr int Bc = 4;
constexpr int Nc = 2048;
constexpr int EcI = Nc * (Nc - 1) / 2;   // 2,096,128 (fits int)
constexpr int EG  = EcI / 4;             // 524,032 groups of 4 per batch

// Stream the PACKED lower triangle (perfect balance), accumulate loss.
// q_target has only 4 distinct values per batch, indexed by (a0, x): LDS table.
__global__ __launch_bounds__(256) void diff_loss_kernel(
    const int* __restrict__ adj, const int* __restrict__ t,
    const float* __restrict__ u, const float* __restrict__ q,
    double* __restrict__ partials)
{
    __shared__ float tab[Bc][8];
    if (threadIdx.x < Bc) {
        int b = threadIdx.x;
        int tb = t[b];
        // Qt[k] built with ts=k+1: flip = 0.5*(1 - 0.98^(k+1))
        float f_t = 0.5f * (1.0f - powf(0.98f, (float)(tb + 1)));
        int tpe = (tb == 0) ? TIMESTEPS : tb;        // Qt[t-1], wrap -1 -> 999
        float f_p = 0.5f * (1.0f - powf(0.98f, (float)tpe));
        float f0  = 0.5f * (1.0f - 0.98f);           // Qt[0] flip
        float omf_t = 1.0f - f_t;
        tab[b][0] = f_t;        // probs1 when a0==0
        tab[b][1] = omf_t;      // probs1 when a0==1
        // q_target(a0,x) = lik1(x)*pri1(a0)/evid(a0,x); evid = (x==a0)?1-f_t:f_t
        tab[b][2] = f0          * f_p          / omf_t;  // a0=0,x=0
        tab[b][3] = (1.0f - f0) * f_p          / f_t;    // a0=0,x=1
        tab[b][4] = f0          * (1.0f - f_p) / f_t;    // a0=1,x=0
        tab[b][5] = (1.0f - f0) * (1.0f - f_p) / omf_t;  // a0=1,x=1
    }
    __syncthreads();

    const int totalEG = Bc * EG;               // 2,096,128
    const int stride = gridDim.x * blockDim.x;
    double acc = 0.0;
    for (int g = blockIdx.x * blockDim.x + threadIdx.x; g < totalEG; g += stride) {
        int b  = g / EG;                       // magic-mul
        int e0 = (g - b * EG) << 2;            // packed index, multiple of 4

        // invert triangular index: largest i with i*(i-1)/2 <= e0
        float sf = sqrtf((float)(8 * e0 + 1));     // 8*e0+1 < 2^24: exact
        int i = (int)((1.0f + sf) * 0.5f);
        if (i * (i - 1) / 2 > e0)  --i;            // fixup rounding
        if (i * (i + 1) / 2 <= e0) ++i;
        int j = e0 - i * (i - 1) / 2;              // 0 <= j < i

        float p0   = tab[b][0], p1   = tab[b][1];
        float qt00 = tab[b][2], qt01 = tab[b][3];
        float qt10 = tab[b][4], qt11 = tab[b][5];

        const float4 q4 = *(const float4*)(q + b * EcI + e0);  // 16B aligned
        const float qk[4] = {q4.x, q4.y, q4.z, q4.w};

        int ii = i, jj = j;
        float s = 0.0f;
        #pragma unroll
        for (int k = 0; k < 4; ++k) {
            // branchless row advance (jj increments by 1 per k; at most one row step)
            bool adv = (jj >= ii);
            ii += adv;
            jj = adv ? 0 : jj;
            int base = (b << 22) + (ii << 11) + jj;
            int   a0 = adj[base];
            float uu = u[base];
            float ps  = a0 ? p1 : p0;
            bool  x   = (uu < ps);
            float t0  = x ? qt01 : qt00;
            float t1  = x ? qt11 : qt10;
            float qtv = a0 ? t1 : t0;
            float qv  = qk[k];
            s += fmaxf(qv, 0.0f) - qv * qtv + __logf(1.0f + __expf(-fabsf(qv)));
            ++jj;
        }
        acc += (double)s;
    }

    // wave (64) shuffle reduce, then cross-wave via LDS
    for (int off = 32; off > 0; off >>= 1)
        acc += __shfl_down(acc, off, 64);
    __shared__ double wsum[4];
    int lane = threadIdx.x & 63, wid = threadIdx.x >> 6;
    if (lane == 0) wsum[wid] = acc;
    __syncthreads();
    if (threadIdx.x == 0)
        partials[blockIdx.x] = wsum[0] + wsum[1] + wsum[2] + wsum[3];
}

// Reduce per-block partials, write mean as f32.
__global__ __launch_bounds__(256) void final_reduce_kernel(
    const double* __restrict__ partials, int nb, float* __restrict__ out)
{
    double acc = 0.0;
    for (int idx = threadIdx.x; idx < nb; idx += blockDim.x)
        acc += partials[idx];
    for (int off = 32; off > 0; off >>= 1)
        acc += __shfl_down(acc, off, 64);
    __shared__ double wsum[4];
    int lane = threadIdx.x & 63, wid = threadIdx.x >> 6;
    if (lane == 0) wsum[wid] = acc;
    __syncthreads();
    if (threadIdx.x == 0)
        out[0] = (float)((wsum[0] + wsum[1] + wsum[2] + wsum[3]) /
                         ((double)Bc * (double)EcI));
}

extern "C" void kernel_launch(void* const* d_in, const int* in_sizes, int n_in,
                              void* d_out, int out_size, void* d_ws, size_t ws_size,
                              hipStream_t stream) {
    const int*   adj = (const int*)d_in[0];   // adj_start (B,N,N) int32
    const int*   t   = (const int*)d_in[1];   // t (B,) int32
    const float* u   = (const float*)d_in[2]; // u (B,N,N) f32
    const float* q   = (const float*)d_in[3]; // q_approx (B,E) f32
    float*  out      = (float*)d_out;
    double* partials = (double*)d_ws;         // NB doubles (16 KB)

    const int NB = 2048;
    diff_loss_kernel<<<NB, 256, 0, stream>>>(adj, t, u, q, partials);
    final_reduce_kernel<<<1, 256, 0, stream>>>(partials, NB, out);
}